// Round 1
// 452.287 us; speedup vs baseline: 1.3216x; 1.3216x over previous
//
#include <hip/hip_runtime.h>
#include <hip/hip_bf16.h>

typedef __attribute__((ext_vector_type(4))) float f32x4;
typedef __attribute__((ext_vector_type(8))) short bf16x8;

__device__ __forceinline__ short f2b(float f) {  // fp32 -> bf16 bits, RNE
  unsigned u = __builtin_bit_cast(unsigned, f);
  u += 0x7FFFu + ((u >> 16) & 1u);
  return (short)(u >> 16);
}
__device__ __forceinline__ float b2f(short s) {
  unsigned u = ((unsigned)(unsigned short)s) << 16;
  return __builtin_bit_cast(float, u);
}

__device__ __forceinline__ void async16(const void* g, void* l) {
  __builtin_amdgcn_global_load_lds(
      (const __attribute__((address_space(1))) void*)g,
      (__attribute__((address_space(3))) void*)l, 16, 0, 0);
}

#define BM 128
#define BN 128
#define BK 64

// Convert fp32 inputs to bf16 workspace: X (8388608 el) then Wq/Wk/Wv/Wo
// (4194304 el each), laid out consecutively from `dst`.
__global__ __launch_bounds__(256) void cvt_kernel(
    const float* __restrict__ X, const float* __restrict__ Wq,
    const float* __restrict__ Wk, const float* __restrict__ Wv,
    const float* __restrict__ Wo, short* __restrict__ dst) {
  const size_t u = (size_t)blockIdx.x * 256 + threadIdx.x;  // unit of 8 elems
  const float* src;
  short* d;
  size_t off;
  if (u < 1048576) {                // X: 1048576 units
    src = X; d = dst; off = u * 8;
  } else {
    const size_t j = u - 1048576;   // 4 x 524288 units
    const int ten = (int)(j >> 19);
    off = (j & 524287) * 8;
    src = (ten == 0) ? Wq : (ten == 1) ? Wk : (ten == 2) ? Wv : Wo;
    d = dst + 8388608 + (size_t)ten * 4194304;
  }
  const f32x4 lo = *(const f32x4*)(src + off);
  const f32x4 hi = *(const f32x4*)(src + off + 4);
  bf16x8 v;
#pragma unroll
  for (int i = 0; i < 4; ++i) { v[i] = f2b(lo[i]); v[i + 4] = f2b(hi[i]); }
  *(bf16x8*)(d + off) = v;
}

// C = A[M,K] @ B[N,K]^T, all-bf16 operands, global_load_lds staging (m97).
// MODE 0: z selects Wq/Wk/Wv; epilogue scatters Q,K [B,H,S,D], V^T [B,H,D,S].
// MODE 1: fp32 row-major output [M,2048] -> d_out.
template <int MODE>
__global__ __launch_bounds__(256, 2) void gemm_kernel(
    const short* __restrict__ A,
    const short* __restrict__ B0,
    const short* __restrict__ B1,
    const short* __restrict__ B2,
    void* __restrict__ O0,
    short* __restrict__ O1,
    short* __restrict__ O2) {
  constexpr int K = 2048;
  const int m0 = blockIdx.x * BM;
  const int n0 = blockIdx.y * BN;
  const short* B;
  if (MODE == 0) {
    const int wsel = blockIdx.z;
    B = (wsel == 0) ? B0 : ((wsel == 1) ? B1 : B2);
  } else {
    B = B0;
  }

  __shared__ __align__(16) short As[BM * BK];  // [row][8 granules, XOR-swizzled]
  __shared__ __align__(16) short Bs[BN * BK];

  const int t = threadIdx.x;
  const int wave = t >> 6;
  const int lane = t & 63;
  const int qd = lane >> 4;  // quad 0..3
  const int ln = lane & 15;
  const int wr = wave >> 1;
  const int wc = wave & 1;

  const f32x4 zero = {0.f, 0.f, 0.f, 0.f};
  f32x4 acc[4][4];
#pragma unroll
  for (int i = 0; i < 4; ++i)
#pragma unroll
    for (int j = 0; j < 4; ++j) acc[i][j] = zero;

  // staging: round r covers row r*32 + (t>>3); LDS slot t&7 holds global
  // granule (t&7)^(row&7). LDS elem for (t, r): r*2048 + t*8 = row*64 + slot*8.
  // LDS dest = wave-uniform base + lane*16B (async16 constraint) ✓
  const int srow = t >> 3;
  const int sgp = (t & 7) ^ (srow & 7);
  const short* Ag = A + (size_t)(m0 + srow) * K + sgp * 8;
  const short* Bg = B + (size_t)(n0 + srow) * K + sgp * 8;
  short* Asw = &As[wave * 512];
  short* Bsw = &Bs[wave * 512];

  for (int k0 = 0; k0 < K; k0 += BK) {
    __syncthreads();
#pragma unroll
    for (int r = 0; r < 4; ++r) {
      async16(Ag + (size_t)(r * 32) * K + k0, Asw + r * 2048);
      async16(Bg + (size_t)(r * 32) * K + k0, Bsw + r * 2048);
    }
    __syncthreads();

    bf16x8 af[2][4], bf[2][4];
#pragma unroll
    for (int kc = 0; kc < 2; ++kc) {
#pragma unroll
      for (int i = 0; i < 4; ++i) {
        const int m = wr * 64 + i * 16 + ln;
        af[kc][i] = *(const bf16x8*)&As[m * BK + (((kc * 4 + qd) ^ (m & 7)) << 3)];
        const int n = wc * 64 + i * 16 + ln;
        bf[kc][i] = *(const bf16x8*)&Bs[n * BK + (((kc * 4 + qd) ^ (n & 7)) << 3)];
      }
    }
#pragma unroll
    for (int kc = 0; kc < 2; ++kc)
#pragma unroll
      for (int i = 0; i < 4; ++i)
#pragma unroll
        for (int j = 0; j < 4; ++j)
          acc[i][j] = __builtin_amdgcn_mfma_f32_16x16x32_bf16(af[kc][i], bf[kc][j],
                                                              acc[i][j], 0, 0, 0);
  }

  // epilogue; C/D layout: col = lane&15, row = quad*4 + reg (m89/m91 verified)
#pragma unroll
  for (int i = 0; i < 4; ++i) {
#pragma unroll
    for (int j = 0; j < 4; ++j) {
      const int n = n0 + wc * 64 + j * 16 + ln;
#pragma unroll
      for (int rr = 0; rr < 4; ++rr) {
        const int m = m0 + wr * 64 + i * 16 + qd * 4 + rr;
        if (MODE == 1) {
          ((float*)O0)[(size_t)m * 2048 + n] = acc[i][j][rr];  // fp32 final out
        } else {
          const short v = f2b(acc[i][j][rr]);
          const int b = m >> 11, s = m & 2047;
          const int h = n >> 7, d = n & 127;
          if (blockIdx.z == 0)
            ((short*)O0)[((size_t)(b * 16 + h) * 2048 + s) * 128 + d] = v;  // Q
          else if (blockIdx.z == 1)
            O1[((size_t)(b * 16 + h) * 2048 + s) * 128 + d] = v;  // K [B,H,S,D]
          else
            O2[((size_t)(b * 16 + h) * 128 + d) * 2048 + s] = v;  // V^T [B,H,D,S]
        }
      }
    }
  }
}

// RoPE in place on Q and K ([B,H,S,D] bf16); thread handles pair (d, d+64).
__global__ void rope_kernel(short* __restrict__ Q,
                            short* __restrict__ Kb,
                            const int* __restrict__ pos_ids) {
  const int idx = blockIdx.x * 256 + threadIdx.x;  // 2*2*16*2048*64 total
  const int d = idx & 63;
  const int row = idx >> 6;       // 0..131071 over {Q,K} x [B,H,S]
  const int tsel = row >> 16;
  const int r = row & 65535;      // (b*16+h)*2048 + s
  const int s = r & 2047;
  const int b = r >> 15;
  const int pos = pos_ids[b * 2048 + s];
  // 10000^(-d/64) = 2^(-d * log2(10000)/64)
  const float invf = __builtin_exp2f(-(float)d * 0.20762050593117475f);
  const float ang = (float)pos * invf;
  const float c = cosf(ang), sn = sinf(ang);
  short* P = (tsel ? Kb : Q) + (size_t)r * 128;
  const float x1 = b2f(P[d]);
  const float x2 = b2f(P[d + 64]);
  P[d] = f2b(x1 * c - x2 * sn);
  P[d + 64] = f2b(x2 * c + x1 * sn);
}

// Flash attention, causal. Block = 4 waves = 64 q rows; kv tiles of 64.
// Q,K: [B,H,S,D]; Vt: [B,H,D,S]; O written [B,S,H*D] bf16.
// LDS = 16K(Ks) + 16K(Vs) + 8K(Ps swizzled) = 40960 B -> 4 blocks/CU.
// qt reversed (longest blocks dispatch first) to kill the causal tail.
// K/V staged via global_load_lds (linear LDS dest + pre-swizzled global src).
__global__ __launch_bounds__(256, 4) void attn_kernel(
    const short* __restrict__ Q,
    const short* __restrict__ Kbuf,
    const short* __restrict__ Vt,
    short* __restrict__ O) {
  const int qt = (int)gridDim.x - 1 - (int)blockIdx.x;  // longest-first
  const int bh = blockIdx.y;  // 0..31
  const int q0 = qt * 64;
  const size_t hoff = (size_t)bh * 2048 * 128;
  const short* Qh = Q + hoff;
  const short* Kh = Kbuf + hoff;
  const short* Vh = Vt + hoff;

  __shared__ __align__(16) short Ks[64 * 128];   // [kv][16 granules, swizzled]
  __shared__ __align__(16) short Vs[128 * 64];   // [d][8 granules, swizzled]
  __shared__ __align__(16) short Ps[4][16 * 64]; // per-wave P, XOR-swizzled

  const int t = threadIdx.x;
  const int wave = t >> 6;
  const int lane = t & 63;
  const int qd = lane >> 4;
  const int ln = lane & 15;

  const int qw0 = q0 + wave * 16;
  bf16x8 qf[4];
  {
    const short* qp = Qh + (size_t)(qw0 + ln) * 128 + qd * 8;
#pragma unroll
    for (int kc = 0; kc < 4; ++kc) qf[kc] = *(const bf16x8*)(qp + kc * 32);
  }

  const f32x4 zero = {0.f, 0.f, 0.f, 0.f};
  f32x4 oacc[8];
#pragma unroll
  for (int dt = 0; dt < 8; ++dt) oacc[dt] = zero;
  float mrow[4] = {-1e30f, -1e30f, -1e30f, -1e30f};
  float lrow[4] = {0.f, 0.f, 0.f, 0.f};

  short* pw = &Ps[wave][0];
  const float rscale = 0.08838834764831845f;  // 1/sqrt(128)

  // staging geometry (global src pre-swizzled; LDS dest linear = async16-ok):
  // K round r: row k0 + r*16 + kr, granule gk -> LDS elem t*8 + r*2048
  // V round r: d-row r*32 + vr,   granule gv -> LDS elem t*8 + r*2048
  const int kr = t >> 4;  // 0..15
  const int gk = (t & 15) ^ (kr & 7);
  const int vr = t >> 3;  // 0..31
  const int gv = (t & 7) ^ (vr & 7);
  const short* Kg = Kh + (size_t)kr * 128 + gk * 8;
  const short* Vg = Vh + (size_t)vr * 2048 + gv * 8;
  short* Ksw = &Ks[wave * 512];
  short* Vsw = &Vs[wave * 512];

  for (int kt = 0; kt <= qt; ++kt) {
    const int k0 = kt * 64;
    __syncthreads();
#pragma unroll
    for (int r = 0; r < 4; ++r) {
      async16(Kg + (size_t)(k0 + r * 16) * 128, Ksw + r * 2048);
      async16(Vg + (size_t)(r * 32) * 2048 + k0, Vsw + r * 2048);
    }
    __syncthreads();  // drains vmcnt before barrier -> LDS writes visible

    // S = Q K^T  (4 col-tiles x 4 d-chunks)
    f32x4 sc[4];
#pragma unroll
    for (int j = 0; j < 4; ++j) {
      sc[j] = zero;
      const int krow = j * 16 + ln;
#pragma unroll
      for (int kc = 0; kc < 4; ++kc) {
        const bf16x8 kf =
            *(const bf16x8*)&Ks[krow * 128 + (((kc * 4 + qd) ^ (krow & 7)) << 3)];
        sc[j] = __builtin_amdgcn_mfma_f32_16x16x32_bf16(qf[kc], kf, sc[j], 0, 0, 0);
      }
    }

    // scale + causal mask (diagonal tile only) + online softmax
    float pv[4][4];
#pragma unroll
    for (int j = 0; j < 4; ++j)
#pragma unroll
      for (int rr = 0; rr < 4; ++rr) pv[j][rr] = sc[j][rr] * rscale;
    if (kt == qt) {  // block-uniform branch; off-diagonal tiles never masked
#pragma unroll
      for (int j = 0; j < 4; ++j) {
        const int kcol = k0 + j * 16 + ln;
#pragma unroll
        for (int rr = 0; rr < 4; ++rr) {
          const int qrow = qw0 + qd * 4 + rr;
          if (kcol > qrow) pv[j][rr] = -1e30f;
        }
      }
    }
    float tmax[4] = {-1e30f, -1e30f, -1e30f, -1e30f};
#pragma unroll
    for (int j = 0; j < 4; ++j)
#pragma unroll
      for (int rr = 0; rr < 4; ++rr) tmax[rr] = fmaxf(tmax[rr], pv[j][rr]);
#pragma unroll
    for (int off = 8; off >= 1; off >>= 1)
#pragma unroll
      for (int rr = 0; rr < 4; ++rr)
        tmax[rr] = fmaxf(tmax[rr], __shfl_xor(tmax[rr], off, 16));

    float alpha[4], psum[4];
#pragma unroll
    for (int rr = 0; rr < 4; ++rr) {
      const float mnew = fmaxf(mrow[rr], tmax[rr]);
      alpha[rr] = __expf(mrow[rr] - mnew);
      mrow[rr] = mnew;
      float ps = 0.f;
#pragma unroll
      for (int j = 0; j < 4; ++j) {
        const float p = __expf(pv[j][rr] - mnew);
        pv[j][rr] = p;
        ps += p;
      }
      psum[rr] = ps;
    }
#pragma unroll
    for (int off = 8; off >= 1; off >>= 1)
#pragma unroll
      for (int rr = 0; rr < 4; ++rr) psum[rr] += __shfl_xor(psum[rr], off, 16);
#pragma unroll
    for (int rr = 0; rr < 4; ++rr) lrow[rr] = lrow[rr] * alpha[rr] + psum[rr];
#pragma unroll
    for (int dt = 0; dt < 8; ++dt)
#pragma unroll
      for (int rr = 0; rr < 4; ++rr) oacc[dt][rr] *= alpha[rr];

    // P: C-layout -> LDS -> A-layout; granule-XOR swizzle (conflict-free read)
#pragma unroll
    for (int j = 0; j < 4; ++j)
#pragma unroll
      for (int rr = 0; rr < 4; ++rr) {
        const int row = qd * 4 + rr;
        const int col = j * 16 + ln;
        pw[row * 64 + (((col >> 3) ^ (row & 7)) << 3) + (col & 7)] =
            f2b(pv[j][rr]);
      }

    bf16x8 pf[2];
#pragma unroll
    for (int kc = 0; kc < 2; ++kc)
      pf[kc] = *(const bf16x8*)&pw[ln * 64 + (((kc * 4 + qd) ^ (ln & 7)) << 3)];

    // O += P V  (8 d-tiles x 2 k-chunks)
#pragma unroll
    for (int dt = 0; dt < 8; ++dt) {
      const int d = dt * 16 + ln;
#pragma unroll
      for (int kc = 0; kc < 2; ++kc) {
        const bf16x8 vf =
            *(const bf16x8*)&Vs[d * 64 + (((kc * 4 + qd) ^ (d & 7)) << 3)];
        oacc[dt] = __builtin_amdgcn_mfma_f32_16x16x32_bf16(pf[kc], vf, oacc[dt], 0, 0, 0);
      }
    }
  }

  const int b = bh >> 4;
  const int h = bh & 15;
  float rl[4];
#pragma unroll
  for (int rr = 0; rr < 4; ++rr) rl[rr] = 1.0f / lrow[rr];
#pragma unroll
  for (int dt = 0; dt < 8; ++dt) {
    const int d = dt * 16 + ln;
#pragma unroll
    for (int rr = 0; rr < 4; ++rr) {
      const int q = qw0 + qd * 4 + rr;
      O[((size_t)(b * 2048 + q)) * 2048 + h * 128 + d] = f2b(oacc[dt][rr] * rl[rr]);
    }
  }
}

extern "C" void kernel_launch(void* const* d_in, const int* in_sizes, int n_in,
                              void* d_out, int out_size, void* d_ws, size_t ws_size,
                              hipStream_t stream) {
  const float* X  = (const float*)d_in[0];  // hidden_states [2,2048,2048] fp32
  // d_in[1] attention_mask: causal, implemented analytically (unused)
  const int* pos  = (const int*)d_in[2];    // position_ids [2,2048] int32
  const float* Wq = (const float*)d_in[3];  // [2048,2048] fp32
  const float* Wk = (const float*)d_in[4];
  const float* Wv = (const float*)d_in[5];
  const float* Wo = (const float*)d_in[6];
  float* out = (float*)d_out;               // fp32 output

  short* ws = (short*)d_ws;
  // bf16 workspace layout (shorts):
  short* Xb  = ws;                       // 8388608
  short* Wqb = ws + 8388608;             // 4194304
  short* Wkb = Wqb + 4194304;
  short* Wvb = Wkb + 4194304;
  short* Wob = Wvb + 4194304;
  short* Qb  = Wob + 4194304;            // 8388608
  short* Kb  = Qb + 8388608;
  short* Vt  = Kb + 8388608;
  short* Ob  = Vt + 8388608;             // total ~112 MB

  cvt_kernel<<<dim3(12288), 256, 0, stream>>>(X, Wq, Wk, Wv, Wo, Xb);
  gemm_kernel<0><<<dim3(32, 16, 3), 256, 0, stream>>>(Xb, Wqb, Wkb, Wvb,
                                                      Qb, Kb, Vt);
  rope_kernel<<<dim3(32768), 256, 0, stream>>>(Qb, Kb, pos);
  attn_kernel<<<dim3(32, 32), 256, 0, stream>>>(Qb, Kb, Vt, Ob);
  gemm_kernel<1><<<dim3(32, 16, 1), 256, 0, stream>>>(Ob, Wob, nullptr, nullptr,
                                                      out, nullptr, nullptr);
}

// Round 3
// 414.082 us; speedup vs baseline: 1.4436x; 1.0923x over previous
//
#include <hip/hip_runtime.h>
#include <hip/hip_bf16.h>

typedef __attribute__((ext_vector_type(4))) float f32x4;
typedef __attribute__((ext_vector_type(8))) short bf16x8;

__device__ __forceinline__ short f2b(float f) {  // fp32 -> bf16 bits, RNE
  unsigned u = __builtin_bit_cast(unsigned, f);
  u += 0x7FFFu + ((u >> 16) & 1u);
  return (short)(u >> 16);
}
__device__ __forceinline__ float b2f(short s) {
  unsigned u = ((unsigned)(unsigned short)s) << 16;
  return __builtin_bit_cast(float, u);
}

__device__ __forceinline__ void async16(const void* g, void* l) {
  __builtin_amdgcn_global_load_lds(
      (const __attribute__((address_space(1))) void*)g,
      (__attribute__((address_space(3))) void*)l, 16, 0, 0);
}

#define BM 128
#define BN 128
#define BK 64

// Convert fp32 inputs to bf16 workspace: X (8388608 el) then Wq/Wk/Wv/Wo
// (4194304 el each), laid out consecutively from `dst`.
__global__ __launch_bounds__(256) void cvt_kernel(
    const float* __restrict__ X, const float* __restrict__ Wq,
    const float* __restrict__ Wk, const float* __restrict__ Wv,
    const float* __restrict__ Wo, short* __restrict__ dst) {
  const size_t u = (size_t)blockIdx.x * 256 + threadIdx.x;  // unit of 8 elems
  const float* src;
  short* d;
  size_t off;
  if (u < 1048576) {                // X: 1048576 units
    src = X; d = dst; off = u * 8;
  } else {
    const size_t j = u - 1048576;   // 4 x 524288 units
    const int ten = (int)(j >> 19);
    off = (j & 524287) * 8;
    src = (ten == 0) ? Wq : (ten == 1) ? Wk : (ten == 2) ? Wv : Wo;
    d = dst + 8388608 + (size_t)ten * 4194304;
  }
  const f32x4 lo = *(const f32x4*)(src + off);
  const f32x4 hi = *(const f32x4*)(src + off + 4);
  bf16x8 v;
#pragma unroll
  for (int i = 0; i < 4; ++i) { v[i] = f2b(lo[i]); v[i + 4] = f2b(hi[i]); }
  *(bf16x8*)(d + off) = v;
}

// C = A[M,K] @ B[N,K]^T, all-bf16 operands, global_load_lds staging (m97).
// MODE 0: z selects Wq/Wk/Wv; epilogue scatters Q,K [B,H,S,D], V^T [B,H,D,S].
// MODE 1: fp32 row-major output [M,2048] -> d_out.
template <int MODE>
__global__ __launch_bounds__(256, 2) void gemm_kernel(
    const short* __restrict__ A,
    const short* __restrict__ B0,
    const short* __restrict__ B1,
    const short* __restrict__ B2,
    void* __restrict__ O0,
    short* __restrict__ O1,
    short* __restrict__ O2) {
  constexpr int K = 2048;
  const int m0 = blockIdx.x * BM;
  const int n0 = blockIdx.y * BN;
  const short* B;
  if (MODE == 0) {
    const int wsel = blockIdx.z;
    B = (wsel == 0) ? B0 : ((wsel == 1) ? B1 : B2);
  } else {
    B = B0;
  }

  __shared__ __align__(16) short As[BM * BK];  // [row][8 granules, XOR-swizzled]
  __shared__ __align__(16) short Bs[BN * BK];

  const int t = threadIdx.x;
  const int wave = t >> 6;
  const int lane = t & 63;
  const int qd = lane >> 4;  // quad 0..3
  const int ln = lane & 15;
  const int wr = wave >> 1;
  const int wc = wave & 1;

  const f32x4 zero = {0.f, 0.f, 0.f, 0.f};
  f32x4 acc[4][4];
#pragma unroll
  for (int i = 0; i < 4; ++i)
#pragma unroll
    for (int j = 0; j < 4; ++j) acc[i][j] = zero;

  // staging: round r covers row r*32 + (t>>3); LDS slot t&7 holds global
  // granule (t&7)^(row&7). LDS elem for (t, r): r*2048 + t*8 = row*64 + slot*8.
  // LDS dest = wave-uniform base + lane*16B (async16 constraint) ✓
  const int srow = t >> 3;
  const int sgp = (t & 7) ^ (srow & 7);
  const short* Ag = A + (size_t)(m0 + srow) * K + sgp * 8;
  const short* Bg = B + (size_t)(n0 + srow) * K + sgp * 8;
  short* Asw = &As[wave * 512];
  short* Bsw = &Bs[wave * 512];

  for (int k0 = 0; k0 < K; k0 += BK) {
    __syncthreads();
#pragma unroll
    for (int r = 0; r < 4; ++r) {
      async16(Ag + (size_t)(r * 32) * K + k0, Asw + r * 2048);
      async16(Bg + (size_t)(r * 32) * K + k0, Bsw + r * 2048);
    }
    __syncthreads();

    bf16x8 af[2][4], bf[2][4];
#pragma unroll
    for (int kc = 0; kc < 2; ++kc) {
#pragma unroll
      for (int i = 0; i < 4; ++i) {
        const int m = wr * 64 + i * 16 + ln;
        af[kc][i] = *(const bf16x8*)&As[m * BK + (((kc * 4 + qd) ^ (m & 7)) << 3)];
        const int n = wc * 64 + i * 16 + ln;
        bf[kc][i] = *(const bf16x8*)&Bs[n * BK + (((kc * 4 + qd) ^ (n & 7)) << 3)];
      }
    }
#pragma unroll
    for (int kc = 0; kc < 2; ++kc)
#pragma unroll
      for (int i = 0; i < 4; ++i)
#pragma unroll
        for (int j = 0; j < 4; ++j)
          acc[i][j] = __builtin_amdgcn_mfma_f32_16x16x32_bf16(af[kc][i], bf[kc][j],
                                                              acc[i][j], 0, 0, 0);
  }

  // epilogue; C/D layout: col = lane&15, row = quad*4 + reg (m89/m91 verified)
#pragma unroll
  for (int i = 0; i < 4; ++i) {
#pragma unroll
    for (int j = 0; j < 4; ++j) {
      const int n = n0 + wc * 64 + j * 16 + ln;
#pragma unroll
      for (int rr = 0; rr < 4; ++rr) {
        const int m = m0 + wr * 64 + i * 16 + qd * 4 + rr;
        if (MODE == 1) {
          ((float*)O0)[(size_t)m * 2048 + n] = acc[i][j][rr];  // fp32 final out
        } else {
          const short v = f2b(acc[i][j][rr]);
          const int b = m >> 11, s = m & 2047;
          const int h = n >> 7, d = n & 127;
          if (blockIdx.z == 0)
            ((short*)O0)[((size_t)(b * 16 + h) * 2048 + s) * 128 + d] = v;  // Q
          else if (blockIdx.z == 1)
            O1[((size_t)(b * 16 + h) * 2048 + s) * 128 + d] = v;  // K [B,H,S,D]
          else
            O2[((size_t)(b * 16 + h) * 128 + d) * 2048 + s] = v;  // V^T [B,H,D,S]
        }
      }
    }
  }
}

// RoPE in place on Q and K ([B,H,S,D] bf16); thread handles pair (d, d+64).
__global__ void rope_kernel(short* __restrict__ Q,
                            short* __restrict__ Kb,
                            const int* __restrict__ pos_ids) {
  const int idx = blockIdx.x * 256 + threadIdx.x;  // 2*2*16*2048*64 total
  const int d = idx & 63;
  const int row = idx >> 6;       // 0..131071 over {Q,K} x [B,H,S]
  const int tsel = row >> 16;
  const int r = row & 65535;      // (b*16+h)*2048 + s
  const int s = r & 2047;
  const int b = r >> 15;
  const int pos = pos_ids[b * 2048 + s];
  // 10000^(-d/64) = 2^(-d * log2(10000)/64)
  const float invf = __builtin_exp2f(-(float)d * 0.20762050593117475f);
  const float ang = (float)pos * invf;
  const float c = cosf(ang), sn = sinf(ang);
  short* P = (tsel ? Kb : Q) + (size_t)r * 128;
  const float x1 = b2f(P[d]);
  const float x2 = b2f(P[d + 64]);
  P[d] = f2b(x1 * c - x2 * sn);
  P[d + 64] = f2b(x2 * c + x1 * sn);
}

// Flash attention, causal. Block = 4 waves = 64 q rows; kv tiles of 32,
// DOUBLE-BUFFERED via global_load_lds, ONE __syncthreads per tile (its
// vmcnt(0) drain is the prefetch wait). LDS = 2*8K(K)+2*8K(V)+4K(P)=36864B
// -> 4 blocks/CU. Work-balanced (qt,bh) map: co-resident stride-256 blocks
// get qt {v,31-v,v,31-v} so every CU sees equal total tiles.
// l accumulated via ones-column MFMA (no psum shuffle); defer-max THR=8.
// FIX (R2->R3): partial-mask guard must be (k0+31 > qw0), not (k0+16 > qw0);
// odd waves' diagonal lands in tile k0 = qw0-16 and was unmasked.
__global__ __launch_bounds__(256, 4) void attn_kernel(
    const short* __restrict__ Q,
    const short* __restrict__ Kbuf,
    const short* __restrict__ Vt,
    short* __restrict__ O) {
  const int n = blockIdx.x;           // 0..1023
  const int v_ = n & 15;
  const int qt = ((n >> 8) & 1) ? (31 - v_) : v_;
  const int bh = ((n >> 4) & 15) | (((n >> 9) & 1) << 4);
  const int q0 = qt * 64;
  const size_t hoff = (size_t)bh * 2048 * 128;
  const short* Qh = Q + hoff;
  const short* Kh = Kbuf + hoff;
  const short* Vh = Vt + hoff;

  __shared__ __align__(16) short Ks[2][32 * 128];  // [buf][kv][16 gran, swz]
  __shared__ __align__(16) short Vs[2][128 * 32];  // [buf][d][4 gran, swz]
  __shared__ __align__(16) short Ps[4][16 * 32];   // per-wave P, swz

  const int t = threadIdx.x;
  const int wave = t >> 6;
  const int lane = t & 63;
  const int qd = lane >> 4;
  const int ln = lane & 15;
  const int qw0 = q0 + wave * 16;

  bf16x8 qf[4];
  {
    const short* qp = Qh + (size_t)(qw0 + ln) * 128 + qd * 8;
#pragma unroll
    for (int kc = 0; kc < 4; ++kc) qf[kc] = *(const bf16x8*)(qp + kc * 32);
  }

  const f32x4 zero = {0.f, 0.f, 0.f, 0.f};
  f32x4 oacc[8];
#pragma unroll
  for (int dt = 0; dt < 8; ++dt) oacc[dt] = zero;
  f32x4 lacc = zero;
  float mrow[4] = {-1e30f, -1e30f, -1e30f, -1e30f};

  bf16x8 ones;
#pragma unroll
  for (int i = 0; i < 8; ++i) ones[i] = (short)0x3F80;  // bf16 1.0

  const float rscale = 0.08838834764831845f;  // 1/sqrt(128)
  short* pw = &Ps[wave][0];

  // staging geometry (global src pre-swizzled; LDS dest linear per async16):
  // K round rd: row rd*16 + (t>>4), slot t&15, gran = slot^(row&7)
  // V round rd: d-row rd*64 + (t>>2), slot t&3, gran = slot^(row&3)
  const int kr = t >> 4;
  const int gk = (t & 15) ^ (kr & 7);
  const int vr = t >> 2;
  const int gv = (t & 3) ^ (vr & 3);
  const short* Kg = Kh + (size_t)kr * 128 + gk * 8;
  const short* Vg = Vh + (size_t)vr * 2048 + gv * 8;
  const int wb = wave * 512;  // per-wave LDS staging base (lane*16B implicit)

  const int nkv = 2 * qt + 2;

  // prologue: stage tile 0 -> buf 0
#pragma unroll
  for (int rd = 0; rd < 2; ++rd) {
    async16(Kg + (size_t)(rd * 16) * 128, &Ks[0][rd * 2048 + wb]);
    async16(Vg + (size_t)rd * 131072, &Vs[0][rd * 2048 + wb]);
  }

  int cur = 0;
  for (int kt = 0; kt < nkv; ++kt) {
    const int k0 = kt * 32;
    __syncthreads();  // vmcnt(0) drain: buf[cur] ready; prior buf[cur^1] reads done
    if (kt + 1 < nkv) {
      const int k1 = k0 + 32;
#pragma unroll
      for (int rd = 0; rd < 2; ++rd) {
        async16(Kg + (size_t)(k1 + rd * 16) * 128, &Ks[cur ^ 1][rd * 2048 + wb]);
        async16(Vg + (size_t)rd * 131072 + k1, &Vs[cur ^ 1][rd * 2048 + wb]);
      }
    }

    if (k0 <= qw0 + 15) {  // wave-uniform: skip fully-masked diagonal subtile
      const short* Kc = &Ks[cur][0];
      f32x4 sc[2];
#pragma unroll
      for (int j = 0; j < 2; ++j) {
        sc[j] = zero;
        const int krow = j * 16 + ln;
#pragma unroll
        for (int kc = 0; kc < 4; ++kc) {
          const bf16x8 kf =
              *(const bf16x8*)&Kc[krow * 128 + (((kc * 4 + qd) ^ (krow & 7)) << 3)];
          sc[j] = __builtin_amdgcn_mfma_f32_16x16x32_bf16(qf[kc], kf, sc[j], 0, 0, 0);
        }
      }

      float pvv[2][4];
#pragma unroll
      for (int j = 0; j < 2; ++j)
#pragma unroll
        for (int rr = 0; rr < 4; ++rr) pvv[j][rr] = sc[j][rr] * rscale;
      if (k0 + 31 > qw0) {  // wave-uniform: partial mask (any col > min row)
#pragma unroll
        for (int j = 0; j < 2; ++j) {
          const int kcol = k0 + j * 16 + ln;
#pragma unroll
          for (int rr = 0; rr < 4; ++rr)
            if (kcol > qw0 + qd * 4 + rr) pvv[j][rr] = -1e30f;
        }
      }

      float tmax[4] = {-1e30f, -1e30f, -1e30f, -1e30f};
#pragma unroll
      for (int j = 0; j < 2; ++j)
#pragma unroll
        for (int rr = 0; rr < 4; ++rr) tmax[rr] = fmaxf(tmax[rr], pvv[j][rr]);
#pragma unroll
      for (int off = 8; off >= 1; off >>= 1)
#pragma unroll
        for (int rr = 0; rr < 4; ++rr)
          tmax[rr] = fmaxf(tmax[rr], __shfl_xor(tmax[rr], off, 16));

      // defer-max: only rescale when max grew by > 8
      bool grow = false;
#pragma unroll
      for (int rr = 0; rr < 4; ++rr) grow = grow || (tmax[rr] > mrow[rr] + 8.f);
      if (__any(grow)) {
#pragma unroll
        for (int rr = 0; rr < 4; ++rr) {
          const float mnew = fmaxf(mrow[rr], tmax[rr]);
          const float al = __expf(mrow[rr] - mnew);
          mrow[rr] = mnew;
          lacc[rr] *= al;
#pragma unroll
          for (int dt = 0; dt < 8; ++dt) oacc[dt][rr] *= al;
        }
      }

      // P: C-layout -> LDS (granule-XOR) -> A-layout
#pragma unroll
      for (int j = 0; j < 2; ++j)
#pragma unroll
        for (int rr = 0; rr < 4; ++rr) {
          const int row = qd * 4 + rr;
          const int col = j * 16 + ln;
          pw[row * 32 + (((col >> 3) ^ (row & 3)) << 3) + (col & 7)] =
              f2b(__expf(pvv[j][rr] - mrow[rr]));
        }
      const bf16x8 pf = *(const bf16x8*)&pw[ln * 32 + ((qd ^ (ln & 3)) << 3)];

      const short* Vc = &Vs[cur][0];
#pragma unroll
      for (int dt = 0; dt < 8; ++dt) {
        const int d = dt * 16 + ln;
        const bf16x8 vf = *(const bf16x8*)&Vc[d * 32 + ((qd ^ (d & 3)) << 3)];
        oacc[dt] = __builtin_amdgcn_mfma_f32_16x16x32_bf16(pf, vf, oacc[dt], 0, 0, 0);
      }
      // l += P @ ones  (row-sum lands in lacc[rr] for row qd*4+rr, any ln)
      lacc = __builtin_amdgcn_mfma_f32_16x16x32_bf16(pf, ones, lacc, 0, 0, 0);
    }
    cur ^= 1;
  }

  const int b = bh >> 4;
  const int h = bh & 15;
  float rl[4];
#pragma unroll
  for (int rr = 0; rr < 4; ++rr) rl[rr] = 1.0f / lacc[rr];
#pragma unroll
  for (int dt = 0; dt < 8; ++dt) {
    const int d = dt * 16 + ln;
#pragma unroll
    for (int rr = 0; rr < 4; ++rr) {
      const int q = qw0 + qd * 4 + rr;
      O[((size_t)(b * 2048 + q)) * 2048 + h * 128 + d] = f2b(oacc[dt][rr] * rl[rr]);
    }
  }
}

extern "C" void kernel_launch(void* const* d_in, const int* in_sizes, int n_in,
                              void* d_out, int out_size, void* d_ws, size_t ws_size,
                              hipStream_t stream) {
  const float* X  = (const float*)d_in[0];  // hidden_states [2,2048,2048] fp32
  // d_in[1] attention_mask: causal, implemented analytically (unused)
  const int* pos  = (const int*)d_in[2];    // position_ids [2,2048] int32
  const float* Wq = (const float*)d_in[3];  // [2048,2048] fp32
  const float* Wk = (const float*)d_in[4];
  const float* Wv = (const float*)d_in[5];
  const float* Wo = (const float*)d_in[6];
  float* out = (float*)d_out;               // fp32 output

  short* ws = (short*)d_ws;
  // bf16 workspace layout (shorts):
  short* Xb  = ws;                       // 8388608
  short* Wqb = ws + 8388608;             // 4194304
  short* Wkb = Wqb + 4194304;
  short* Wvb = Wkb + 4194304;
  short* Wob = Wvb + 4194304;
  short* Qb  = Wob + 4194304;            // 8388608
  short* Kb  = Qb + 8388608;
  short* Vt  = Kb + 8388608;
  short* Ob  = Vt + 8388608;             // total ~112 MB

  cvt_kernel<<<dim3(12288), 256, 0, stream>>>(X, Wq, Wk, Wv, Wo, Xb);
  gemm_kernel<0><<<dim3(32, 16, 3), 256, 0, stream>>>(Xb, Wqb, Wkb, Wvb,
                                                      Qb, Kb, Vt);
  rope_kernel<<<dim3(32768), 256, 0, stream>>>(Qb, Kb, pos);
  attn_kernel<<<dim3(1024), 256, 0, stream>>>(Qb, Kb, Vt, Ob);
  gemm_kernel<1><<<dim3(32, 16, 1), 256, 0, stream>>>(Ob, Wob, nullptr, nullptr,
                                                      out, nullptr, nullptr);
}